// Round 5
// baseline (230.399 us; speedup 1.0000x reference)
//
#include <hip/hip_runtime.h>
#include <hip/hip_bf16.h>
#include <math.h>

#define NB 2
#define NH 16
#define NS 2048
#define ND 128

typedef __bf16 bf16x8 __attribute__((ext_vector_type(8)));
typedef __bf16 bf16x4 __attribute__((ext_vector_type(4)));
typedef float f32x4 __attribute__((ext_vector_type(4)));

#define KTILE 64
#define KSTR 136   // K lds row stride: b128 reads uniform 8-deep (min)
#define VSTR 72    // Vt row stride
#define PSTR 80    // 160B rows == 8 banks mod 32 -> quad b16-write segments disjoint

// R5: LDS-pipe-bound fix. QTILE=128 (32 q-rows/wave) halves per-q-row LDS
// fragment reads vs R4. Uniform blocks via complementary q-tile pairs
// (15-pr, pr): every block = exactly 34 KV tiles. Grid=256, 1 block/CU,
// 4 waves. PSTR=80 makes P b16 stores conflict-minimal (depth 2).

__global__ __launch_bounds__(256, 1)
void fa_fwd(const float* __restrict__ Qg_, const float* __restrict__ Kg_,
            const float* __restrict__ Vg_, float* __restrict__ Out)
{
    __shared__ __bf16 Kl[KTILE][KSTR];
    __shared__ __bf16 Vt[ND + 16][VSTR];   // rows 128..143: ones-row (row-sum trick)
    __shared__ __bf16 Pl[4][32][PSTR];

    const int tid  = threadIdx.x;
    const int w    = tid >> 6;
    const int lane = tid & 63;
    const int quad = lane >> 4;
    const int l15  = lane & 15;

    const int pr = blockIdx.x >> 5;        // 0..7
    const int bh = blockIdx.x & 31;
    const int b  = bh >> 4;
    const int h  = bh & 15;
    const int qtA = 15 - pr, qtB = pr;     // q-tiles of 128 rows
    const int ntA = 2*qtA + 2;             // KV units for phase A
    const int total = ntA + 2*qtB + 2;     // always 34

    const float* Qg = Qg_ + (size_t)bh * NS * ND;
    const float* Kg = Kg_ + (size_t)bh * NS * ND;
    const float* Vg = Vg_ + (size_t)bh * NS * ND;

    for (int i = tid; i < 16*VSTR; i += 256) {
        int r = i / VSTR, c = i - r*VSTR;
        Vt[ND + r][c] = (r == 0) ? (__bf16)1.0f : (__bf16)0.0f;
    }

    const float CSC = 0.08838834764831845f * 1.4426950408889634f;

    const int qA = qtA * 128, qB = qtB * 128;

    // load Q fragments (scaled) for a given q-base: A[m=l15][k=quad*8+j]
    bf16x8 qf[2][4];
    auto load_q = [&](int qbase) {
        #pragma unroll
        for (int rt = 0; rt < 2; ++rt) {
            const float* qp = Qg + (size_t)(qbase + 32*w + 16*rt + l15) * ND + quad*8;
            #pragma unroll
            for (int ks = 0; ks < 4; ++ks) {
                float4 a = *(const float4*)(qp + ks*32);
                float4 c = *(const float4*)(qp + ks*32 + 4);
                bf16x8 f;
                f[0]=(__bf16)(a.x*CSC); f[1]=(__bf16)(a.y*CSC); f[2]=(__bf16)(a.z*CSC); f[3]=(__bf16)(a.w*CSC);
                f[4]=(__bf16)(c.x*CSC); f[5]=(__bf16)(c.y*CSC); f[6]=(__bf16)(c.z*CSC); f[7]=(__bf16)(c.w*CSC);
                qf[rt][ks] = f;
            }
        }
    };
    load_q(qA);

    f32x4 O[2][9];   // dt=8 = row sums via ones-row
    #pragma unroll
    for (int rt = 0; rt < 2; ++rt)
        #pragma unroll
        for (int dt = 0; dt < 9; ++dt)
            #pragma unroll
            for (int r = 0; r < 4; ++r) O[rt][dt][r] = 0.0f;

    auto flush = [&](int qbase) {
        #pragma unroll
        for (int rt = 0; rt < 2; ++rt) {
            #pragma unroll
            for (int r = 0; r < 4; ++r) {
                float lsum = __shfl(O[rt][8][r], lane & 48, 64);
                float inv = 1.0f / lsum;
                int q = qbase + 32*w + 16*rt + quad*4 + r;
                float* op = Out + ((size_t)(b*NS + q)) * (NH*ND) + h*ND + l15;
                #pragma unroll
                for (int dt = 0; dt < 8; ++dt)
                    op[dt*16] = O[rt][dt][r] * inv;
            }
        }
    };

    // prefetch registers
    float4 kp[8];
    float  vp[32];
    const int vc = tid & 127;
    const int vh = tid >> 7;

    {   // prefetch tile 0
        #pragma unroll
        for (int i = 0; i < 8; ++i)
            kp[i] = *(const float4*)(Kg + ((i*256 + tid) << 2));
        const float* vs = Vg + (size_t)(vh*32) * ND + vc;
        #pragma unroll
        for (int i = 0; i < 32; ++i) vp[i] = vs[i*ND];
    }

    for (int t = 0; t < total; ++t) {
        const int phase = (t >= ntA);
        const int jt  = phase ? t - ntA : t;
        const int kv0 = jt * KTILE;
        __syncthreads();   // prior tile's reads done

        // ---- regs -> LDS ----
        #pragma unroll
        for (int i = 0; i < 8; ++i) {
            int idx = (i*256 + tid) << 2;
            int r = idx >> 7, c = idx & 127;
            bf16x4 f; f[0]=(__bf16)kp[i].x; f[1]=(__bf16)kp[i].y; f[2]=(__bf16)kp[i].z; f[3]=(__bf16)kp[i].w;
            *(bf16x4*)&Kl[r][c] = f;
        }
        #pragma unroll
        for (int g = 0; g < 4; ++g) {
            bf16x8 f;
            #pragma unroll
            for (int j = 0; j < 8; ++j) f[j] = (__bf16)vp[g*8 + j];
            *(bf16x8*)&Vt[vc][vh*32 + g*8] = f;
        }

        // ---- prefetch t+1 ----
        if (t + 1 < total) {
            const int jt2 = (t + 1 >= ntA) ? t + 1 - ntA : t + 1;
            const int kv1 = jt2 * KTILE;
            const float* ks2 = Kg + (size_t)kv1 * ND;
            #pragma unroll
            for (int i = 0; i < 8; ++i)
                kp[i] = *(const float4*)(ks2 + ((i*256 + tid) << 2));
            const float* vs = Vg + (size_t)(kv1 + vh*32) * ND + vc;
            #pragma unroll
            for (int i = 0; i < 32; ++i) vp[i] = vs[i*ND];
        }

        __syncthreads();   // LDS ready

        if (t == ntA) {
            flush(qA);     // phase A complete
            #pragma unroll
            for (int rt = 0; rt < 2; ++rt)
                #pragma unroll
                for (int dt = 0; dt < 9; ++dt)
                    #pragma unroll
                    for (int r = 0; r < 4; ++r) O[rt][dt][r] = 0.0f;
            load_q(qB);
        }

        const int qbase = phase ? qB : qA;
        const int qtX   = phase ? qtB : qtA;

        // ---- S = Q K^T (both rt share K frags) ----
        f32x4 Sf[2][4];
        #pragma unroll
        for (int rt = 0; rt < 2; ++rt)
            #pragma unroll
            for (int n = 0; n < 4; ++n)
                #pragma unroll
                for (int r = 0; r < 4; ++r) Sf[rt][n][r] = 0.0f;
        #pragma unroll
        for (int ks = 0; ks < 4; ++ks) {
            bf16x8 bf[4];
            #pragma unroll
            for (int n = 0; n < 4; ++n)
                bf[n] = *(const bf16x8*)&Kl[n*16 + l15][ks*32 + quad*8];
            #pragma unroll
            for (int rt = 0; rt < 2; ++rt)
                #pragma unroll
                for (int n = 0; n < 4; ++n)
                    Sf[rt][n] = __builtin_amdgcn_mfma_f32_16x16x32_bf16(qf[rt][ks], bf[n], Sf[rt][n], 0, 0, 0);
        }

        // ---- mask + exp2 -> P (row-permuted: m=4q+r stored at 4r+q) ----
        bool skip_rt[2];
        #pragma unroll
        for (int rt = 0; rt < 2; ++rt) {
            const int qb = qbase + 32*w + 16*rt;
            skip_rt[rt] = (kv0 > qb + 15);
            if (skip_rt[rt]) continue;
            const bool diag = (kv0 + KTILE - 1 > qb);
            #pragma unroll
            for (int n = 0; n < 4; ++n) {
                const int kg = kv0 + n*16 + l15;
                #pragma unroll
                for (int r = 0; r < 4; ++r) {
                    float tv = Sf[rt][n][r];
                    if (diag) {
                        int qg = qb + quad*4 + r;
                        if (kg > qg) tv = -INFINITY;
                    }
                    Pl[w][16*rt + r*4 + quad][n*16 + l15] = (__bf16)exp2f(tv);
                }
            }
        }

        // ---- O += P V ----
        #pragma unroll
        for (int ks = 0; ks < 2; ++ks) {
            bf16x8 af[2];
            #pragma unroll
            for (int rt = 0; rt < 2; ++rt)
                if (!skip_rt[rt])
                    af[rt] = *(const bf16x8*)&Pl[w][16*rt + (((l15 & 3) << 2) | (l15 >> 2))][ks*32 + quad*8];
            #pragma unroll
            for (int dt = 0; dt < 9; ++dt) {
                bf16x8 vf = *(const bf16x8*)&Vt[dt*16 + l15][ks*32 + quad*8];
                #pragma unroll
                for (int rt = 0; rt < 2; ++rt)
                    if (!skip_rt[rt])
                        O[rt][dt] = __builtin_amdgcn_mfma_f32_16x16x32_bf16(af[rt], vf, O[rt][dt], 0, 0, 0);
            }
        }
    }

    flush(qB);
}

extern "C" void kernel_launch(void* const* d_in, const int* in_sizes, int n_in,
                              void* d_out, int out_size, void* d_ws, size_t ws_size,
                              hipStream_t stream) {
    const float* Q = (const float*)d_in[0];
    const float* K = (const float*)d_in[1];
    const float* V = (const float*)d_in[2];
    float* Out = (float*)d_out;
    dim3 grid(256);   // 32 bh * 8 complement pairs, all uniform (34 tiles)
    fa_fwd<<<grid, dim3(256), 0, stream>>>(Q, K, V, Out);
}